// Round 6
// baseline (9426.064 us; speedup 1.0000x reference)
//
#include <hip/hip_runtime.h>
#include <hip/hip_bf16.h>

#define S_LEN 256
#define NB 32
#define UDIM 512
#define RING 8

typedef __attribute__((ext_vector_type(8))) short bf16x8;
typedef __attribute__((ext_vector_type(4))) float f32x4;
typedef __attribute__((ext_vector_type(4))) unsigned u32x4;

struct WPtrs { const float* p[8]; };
struct BPtrs { const float* p[4]; };

__device__ __forceinline__ unsigned short f2bf(float f) {
  union { float f; unsigned u; } v; v.f = f;
  unsigned r = v.u + 0x7fffu + ((v.u >> 16) & 1u);
  return (unsigned short)(r >> 16);
}
union QU { u32x4 u; bf16x8 b; };
__device__ __forceinline__ bf16x8 q2b(u32x4 v) { QU x; x.u = v; return x.b; }

// device-scope (cross-XCD) store: write-through to coherent point
__device__ __forceinline__ void st_u32c(void* p, unsigned v) {
  asm volatile("global_store_dword %0, %1, off sc0 sc1" :: "v"(p), "v"(v) : "memory");
}

// 16 dwordx4 loads (2 A-rows x 8 k-chunks), waitcnt INSIDE the asm block:
// outputs are final at retirement -- no issue/wait split, no spill hazard.
#define GL16(F) \
  "global_load_dwordx4 %0, %16, off " F "\n\t" \
  "global_load_dwordx4 %1, %16, off offset:64 " F "\n\t" \
  "global_load_dwordx4 %2, %16, off offset:128 " F "\n\t" \
  "global_load_dwordx4 %3, %16, off offset:192 " F "\n\t" \
  "global_load_dwordx4 %4, %16, off offset:256 " F "\n\t" \
  "global_load_dwordx4 %5, %16, off offset:320 " F "\n\t" \
  "global_load_dwordx4 %6, %16, off offset:384 " F "\n\t" \
  "global_load_dwordx4 %7, %16, off offset:448 " F "\n\t" \
  "global_load_dwordx4 %8, %17, off " F "\n\t" \
  "global_load_dwordx4 %9, %17, off offset:64 " F "\n\t" \
  "global_load_dwordx4 %10, %17, off offset:128 " F "\n\t" \
  "global_load_dwordx4 %11, %17, off offset:192 " F "\n\t" \
  "global_load_dwordx4 %12, %17, off offset:256 " F "\n\t" \
  "global_load_dwordx4 %13, %17, off offset:320 " F "\n\t" \
  "global_load_dwordx4 %14, %17, off offset:384 " F "\n\t" \
  "global_load_dwordx4 %15, %17, off offset:448 " F "\n\t" \
  "s_waitcnt vmcnt(0)"

#define QOUT(q) "=&v"((q)[0]),"=&v"((q)[1]),"=&v"((q)[2]),"=&v"((q)[3]),"=&v"((q)[4]), \
                "=&v"((q)[5]),"=&v"((q)[6]),"=&v"((q)[7]),"=&v"((q)[8]),"=&v"((q)[9]), \
                "=&v"((q)[10]),"=&v"((q)[11]),"=&v"((q)[12]),"=&v"((q)[13]),"=&v"((q)[14]),"=&v"((q)[15])

// coherent-point blocking 16-load (cross-XCD safe)
__device__ __forceinline__ void ld16_coh(const short* p0, const short* p1, u32x4* q) {
  asm volatile(GL16("sc0 sc1") : QOUT(q) : "v"(p0), "v"(p1) : "memory");
}
// L1-bypass blocking 16-load (reads own-XCD L2: used only on verified-same-XCD data)
__device__ __forceinline__ void ld16_fast(const short* p0, const short* p1, u32x4* q) {
  asm volatile(GL16("sc0") : QOUT(q) : "v"(p0), "v"(p1) : "memory");
}

__device__ __forceinline__ bool okq(const u32x4* q) {
  const unsigned S = 0xFFFFFFFFu;
  bool bad = false;
#pragma unroll
  for (int i = 0; i < 16; ++i)
    bad |= (q[i][0] == S) | (q[i][1] == S) | (q[i][2] == S) | (q[i][3] == S);
  return !bad;
}
// poll coherent data until sentinel-free
__device__ __forceinline__ void pollx(const short* p0, const short* p1, u32x4* q) {
  ld16_coh(p0, p1, q);
  while (!__all(okq(q))) { __builtin_amdgcn_s_sleep(1); ld16_coh(p0, p1, q); }
}

// ---------------- embedding gather + mask ----------------
__global__ void k_embed(const int* __restrict__ x, const float* __restrict__ tab,
                        unsigned short* __restrict__ emb, int* __restrict__ mask) {
  int t = blockIdx.x, b = blockIdx.y;
  int tok = x[b * S_LEN + t];
  if (threadIdx.x == 0) mask[t * NB + b] = (tok != 0);
  const float4* src = (const float4*)(tab + (size_t)tok * UDIM);
  ushort4* dst = (ushort4*)(emb + ((size_t)t * NB + b) * UDIM);
  int i = threadIdx.x;
  float4 v = src[i];
  ushort4 o;
  o.x = f2bf(v.x); o.y = f2bf(v.y); o.z = f2bf(v.z); o.w = f2bf(v.w);
  dst[i] = o;
}

// ---------------- weight transpose/convert ----------------
__global__ void k_wprep(WPtrs wp, unsigned short* __restrict__ wsW) {
  int bid = blockIdx.x;
  int kt = bid & 31; bid >>= 5;
  int g  = bid % 3;  bid /= 3;
  int wg = bid & 31; bid >>= 5;
  int slab = bid;                        // 0..7 : (chain, mat)
  const float* src = wp.p[slab];
  int tid = threadIdx.x;
  int r = tid >> 4, cc = tid & 15;
  __shared__ float ldsT[16][17];
  ldsT[cc][r] = src[(size_t)(kt * 16 + r) * 1536 + g * 512 + wg * 16 + cc];
  __syncthreads();
  size_t off = ((size_t)slab * 32 + wg) * (48 * 512) + (size_t)(g * 16 + r) * 512 + kt * 16 + cc;
  wsW[off] = f2bf(ldsT[r][cc]);
}

// ---------------- persistent recurrent kernel ----------------
// 256 WGs x 256 thr, 96KB+ LDS forces 1 WG/CU -> exactly 32 WGs per XCD.
// Each WG reads its REAL XCC_ID; chain c = xcd&3 is claimed by one XCD via
// device-scope CAS; that XCD's 32 WGs take units 0..31. Intra-chain h
// exchange: plain-store ring + sc0 sentinel poll (same-XCD L2, verified by
// construction). Cross-chain + fallback: coherent shadow (sc0 sc1).
__global__ __launch_bounds__(256, 1) void k_rnn(
    const unsigned short* __restrict__ wsW, const unsigned short* __restrict__ emb,
    unsigned short* __restrict__ hring, unsigned short* __restrict__ shadow,
    const int* __restrict__ mask, const float* __restrict__ state,
    BPtrs bp, float* __restrict__ out, int* __restrict__ owner, int* __restrict__ cnt) {
  __shared__ short sW[2 * 48 * 512];      // 96 KB, XOR-swizzled rows
  __shared__ float sAcc[2][2][32][49];    // padded stride 49 (kills 4-way write conflicts)
  __shared__ float sBias[2][48];
  __shared__ unsigned char sMask[S_LEN][NB];
  __shared__ int sAssign[2];

  int tid = threadIdx.x;
  // ---- placement-aware assignment ----
  if (tid == 0) {
    int xcd;
    asm volatile("s_getreg_b32 %0, hwreg(HW_REG_XCC_ID)" : "=s"(xcd));
    xcd &= 7;
    int chain = xcd & 3;
    int expected = -1;
    __hip_atomic_compare_exchange_strong(&owner[chain], &expected, xcd,
        __ATOMIC_ACQ_REL, __ATOMIC_ACQUIRE, __HIP_MEMORY_SCOPE_AGENT);
    int own = __hip_atomic_load(&owner[chain], __ATOMIC_ACQUIRE, __HIP_MEMORY_SCOPE_AGENT);
    int unit = -1;
    if (own == xcd)
      unit = __hip_atomic_fetch_add(&cnt[chain], 1, __ATOMIC_RELAXED, __HIP_MEMORY_SCOPE_AGENT);
    sAssign[0] = chain; sAssign[1] = unit;
  }
  __syncthreads();
  int c = sAssign[0];
  int w = sAssign[1];
  if (w < 0 || w >= 32) return;           // non-owner XCD: idle-exit

  int layer = c & 1;
  bool back = (c >= 2);
  int lane = tid & 63;
  int wave = tid >> 6;
  int mat = wave & 1;                     // 0: x@k, 1: h@rk
  int kh = wave >> 1;                     // K-half
  int cb = tid >> 3;                      // combine ownership: (b, j0, j0+1)
  int cj = (tid & 7) << 1;
  float hreg0, hreg1, preg0 = 0.f, preg1 = 0.f;

  // ---- init: weights -> LDS (swizzled), biases, mask, state ----
  {
    const size_t slabSz = 48 * 512;
    for (int ch = tid; ch < 2 * 48 * 64; ch += 256) {
      int m = ch / (48 * 64);
      int rem = ch % (48 * 64);
      int nl = rem >> 6;
      int k16 = rem & 63;
      const unsigned short* sp =
          wsW + ((size_t)((c * 2 + m) * 32) + w) * slabSz + (size_t)nl * 512 + k16 * 8;
      bf16x8 val = *(const bf16x8*)sp;
      int byt = m * 49152 + nl * 1024 + ((k16 * 16) ^ ((nl & 7) << 4));
      *(bf16x8*)((char*)sW + byt) = val;
    }
    const float* bptr = bp.p[c];
    for (int i = tid; i < 96; i += 256) {
      int m = i / 48, nl = i % 48;
      int col = (nl / 16) * 512 + w * 16 + (nl & 15);
      sBias[m][nl] = bptr[m * 1536 + col];
    }
    for (int i = tid; i < S_LEN * NB; i += 256)
      sMask[i >> 5][i & 31] = (unsigned char)(mask[i] != 0);
    int col = w * 16 + cj;
    hreg0 = state[((size_t)c * NB + cb) * UDIM + col];
    hreg1 = state[((size_t)c * NB + cb) * UDIM + col + 1];
    unsigned pk = (unsigned)f2bf(hreg0) | ((unsigned)f2bf(hreg1) << 16);
    // ring slot 0 (plain -> L2) + shadow slot 0 (coherent)
    *(unsigned*)(hring + (((size_t)c * RING + 0) * NB + cb) * UDIM + col) = pk;
    st_u32c((unsigned*)(shadow + (((size_t)c * 257 + 0) * NB + cb) * UDIM + col), pk);
  }
  __syncthreads();

  bool latched = false;                   // sticky fallback to coherent shadow
  int r15 = lane & 15, quad = lane >> 4;
  int abase = r15 * UDIM + kh * 256 + quad * 8;
  int matbase = mat * 49152;

  for (int t = 0; t < S_LEN; ++t) {
    int treal = back ? (S_LEN - 1 - t) : t;
    u32x4 q[16];

    if (mat == 0) {
      if (layer == 0) {
        const short* a16 = (const short*)(emb + (size_t)treal * NB * UDIM);
#pragma unroll
        for (int kc = 0; kc < 8; ++kc) {
          q[kc]     = *(const u32x4*)(a16 + abase + kc * 32);
          q[kc + 8] = *(const u32x4*)(a16 + abase + 16 * UDIM + kc * 32);
        }
      } else {
        const short* a16 = (const short*)(shadow + ((size_t)(c - 1) * 257 + (t + 1)) * NB * UDIM);
        pollx(a16 + abase, a16 + abase + 16 * UDIM, q);
      }
    } else {
      const short* rb = (const short*)(hring + ((size_t)c * RING + (t & 7)) * NB * UDIM);
      const short* p0 = rb + abase;
      const short* p1 = p0 + 16 * UDIM;
      if (!latched) {
        ld16_fast(p0, p1, q);
        int tries = 0;
        while (!__all(okq(q))) {
          if (++tries > 4096) { latched = true; break; }
          __builtin_amdgcn_s_sleep(1);
          ld16_fast(p0, p1, q);
        }
      }
      if (latched) {
        const short* sb = (const short*)(shadow + ((size_t)c * 257 + t) * NB * UDIM);
        pollx(sb + abase, sb + abase + 16 * UDIM, q);
      }
    }

    // ---- GEMM: (32 x 48) += A(32 x 256-half) * W(256-half x 48) ----
    f32x4 acc[2][3];
#pragma unroll
    for (int a = 0; a < 2; a++)
#pragma unroll
      for (int g = 0; g < 3; g++) acc[a][g] = (f32x4){0.f, 0.f, 0.f, 0.f};
#pragma unroll
    for (int kc = 0; kc < 8; ++kc) {
      bf16x8 a0 = q2b(q[kc]);
      bf16x8 a1 = q2b(q[kc + 8]);
#pragma unroll
      for (int g = 0; g < 3; ++g) {
        int nl = g * 16 + r15;
        int koff = kh * 512 + kc * 64 + quad * 16;
        int byt = matbase + nl * 1024 + (koff ^ ((nl & 7) << 4));
        bf16x8 bw = *(const bf16x8*)((const char*)sW + byt);
        acc[0][g] = __builtin_amdgcn_mfma_f32_16x16x32_bf16(a0, bw, acc[0][g], 0, 0, 0);
        acc[1][g] = __builtin_amdgcn_mfma_f32_16x16x32_bf16(a1, bw, acc[1][g], 0, 0, 0);
      }
    }
#pragma unroll
    for (int mt = 0; mt < 2; ++mt)
#pragma unroll
      for (int g = 0; g < 3; ++g)
#pragma unroll
        for (int rr = 0; rr < 4; ++rr)
          sAcc[kh][mat][mt * 16 + quad * 4 + rr][g * 16 + r15] = acc[mt][g][rr];
    __syncthreads();

    // ---- combine + GRU nonlinearity ----
    {
      int b = cb, j0 = cj;
      bool m = sMask[treal][b] != 0;
      float hn0, hn1;
#pragma unroll
      for (int u = 0; u < 2; ++u) {
        int j = j0 + u;
        float az = sAcc[0][0][b][j]      + sAcc[1][0][b][j]      + sBias[0][j];
        float ar = sAcc[0][0][b][16 + j] + sAcc[1][0][b][16 + j] + sBias[0][16 + j];
        float ah = sAcc[0][0][b][32 + j] + sAcc[1][0][b][32 + j] + sBias[0][32 + j];
        float iz = sAcc[0][1][b][j]      + sAcc[1][1][b][j]      + sBias[1][j];
        float ir = sAcc[0][1][b][16 + j] + sAcc[1][1][b][16 + j] + sBias[1][16 + j];
        float ih = sAcc[0][1][b][32 + j] + sAcc[1][1][b][32 + j] + sBias[1][32 + j];
        float z = 1.f / (1.f + __expf(-(az + iz)));
        float r = 1.f / (1.f + __expf(-(ar + ir)));
        float pre = ah + r * ih;
        pre = fminf(fmaxf(pre, -30.f), 30.f);
        float e2 = __expf(2.f * pre);
        float hh = (e2 - 1.f) / (e2 + 1.f);
        float hold = (u == 0) ? hreg0 : hreg1;
        float hv = z * hold + (1.f - z) * hh;
        hv = m ? hv : hold;
        if (u == 0) hn0 = hv; else hn1 = hv;
      }
      hreg0 = hn0; hreg1 = hn1;
      unsigned pk = (unsigned)f2bf(hn0) | ((unsigned)f2bf(hn1) << 16);
      int col = w * 16 + j0;
      if (t < S_LEN - 1) {
        // ring publish h(t+1) + sentinel-reset slot h(t-3) (plain, L2-local)
        *(unsigned*)(hring + (((size_t)c * RING + ((t + 1) & 7)) * NB + b) * UDIM + col) = pk;
        *(unsigned*)(hring + (((size_t)c * RING + ((t + 5) & 7)) * NB + b) * UDIM + col) =
            0xFFFFFFFFu;
      }
      // coherent shadow publish (cross-chain feed for layer0; fallback for all)
      st_u32c((unsigned*)(shadow + (((size_t)c * 257 + (t + 1)) * NB + b) * UDIM + col), pk);
      if (layer == 1) {
        float o0 = m ? hn0 : preg0;
        float o1 = m ? hn1 : preg1;
        preg0 = o0; preg1 = o1;
        *(float2*)(out + ((size_t)b * S_LEN + treal) * 1024 + (back ? 512 : 0) + col) =
            make_float2(o0, o1);
      }
      if (t == S_LEN - 1) {
        *(float2*)(out + (size_t)NB * S_LEN * 1024 + ((size_t)c * NB + b) * UDIM + col) =
            make_float2(hn0, hn1);
      }
    }
    __syncthreads();   // WAR guard on sAcc before next step's GEMM writes
  }
}

extern "C" void kernel_launch(void* const* d_in, const int* in_sizes, int n_in,
                              void* d_out, int out_size, void* d_ws, size_t ws_size,
                              hipStream_t stream) {
  const int* x = (const int*)d_in[0];
  const float* state = (const float*)d_in[1];
  const float* tab = (const float*)d_in[2];
  WPtrs wp;
  wp.p[0] = (const float*)d_in[3];   // fk0
  wp.p[1] = (const float*)d_in[4];   // frk0
  wp.p[2] = (const float*)d_in[6];   // fk1
  wp.p[3] = (const float*)d_in[7];   // frk1
  wp.p[4] = (const float*)d_in[9];   // bk0
  wp.p[5] = (const float*)d_in[10];  // brk0
  wp.p[6] = (const float*)d_in[12];  // bk1
  wp.p[7] = (const float*)d_in[13];  // brk1
  BPtrs bp;
  bp.p[0] = (const float*)d_in[5];   // fb0
  bp.p[1] = (const float*)d_in[8];   // fb1
  bp.p[2] = (const float*)d_in[11];  // bb0
  bp.p[3] = (const float*)d_in[14];  // bb1
  float* out = (float*)d_out;

  char* ws = (char*)d_ws;
  size_t off = 0;
  unsigned short* wsW = (unsigned short*)(ws + off); off += (size_t)8 * 32 * 48 * 512 * 2;   // 25.2 MB
  unsigned short* embp = (unsigned short*)(ws + off); off += (size_t)S_LEN * NB * UDIM * 2;  // 8.4 MB
  int* maskp = (int*)(ws + off); off += (size_t)S_LEN * NB * 4;
  unsigned short* hring = (unsigned short*)(ws + off);
  size_t ringBytes = (size_t)4 * RING * NB * UDIM * 2;   off += ringBytes;                   // 1 MB
  unsigned short* shadow = (unsigned short*)(ws + off);
  size_t shBytes = (size_t)4 * 257 * NB * UDIM * 2;      off += shBytes;                     // 33.7 MB
  int* owner = (int*)(ws + off); off += 16;
  int* cntp  = (int*)(ws + off); off += 16;

  hipMemsetAsync(hring, 0xFF, ringBytes + shBytes, stream);  // ring+shadow poison
  hipMemsetAsync(owner, 0xFF, 16, stream);                    // owner = -1
  hipMemsetAsync(cntp, 0, 16, stream);                        // cnt = 0
  k_embed<<<dim3(S_LEN, NB), 128, 0, stream>>>(x, tab, embp, maskp);
  k_wprep<<<8 * 32 * 3 * 32, 256, 0, stream>>>(wp, wsW);
  k_rnn<<<256, 256, 0, stream>>>(wsW, embp, hring, shadow, maskp, state, bp, out, owner, cntp);
}

// Round 7
// 1129.712 us; speedup vs baseline: 8.3438x; 8.3438x over previous
//
#include <hip/hip_runtime.h>
#include <hip/hip_bf16.h>

#define S_LEN 256
#define NB 32
#define UDIM 512
#define WGS 32    // workgroups per chain
#define NH 16     // h-columns owned per WG

typedef __attribute__((ext_vector_type(8))) short bf16x8;
typedef __attribute__((ext_vector_type(4))) float f32x4;
typedef __attribute__((ext_vector_type(4))) unsigned u32x4;

struct WPtrs { const float* p[8]; };
struct BPtrs { const float* p[4]; };

__device__ __forceinline__ unsigned short f2bf(float f) {
  union { float f; unsigned u; } v; v.f = f;
  unsigned r = v.u + 0x7fffu + ((v.u >> 16) & 1u);
  return (unsigned short)(r >> 16);
}

// ---- coherent (cross-XCD) memory ops: sc0 sc1, no cache flushes ----
__device__ __forceinline__ int ld_flag(const int* p) {
  int v;
  asm volatile("global_load_dword %0, %1, off sc0 sc1\n\ts_waitcnt vmcnt(0)"
               : "=&v"(v) : "v"(p) : "memory");
  return v;
}
__device__ __forceinline__ void st_u32c(unsigned* p, unsigned v) {
  asm volatile("global_store_dword %0, %1, off sc0 sc1" :: "v"(p), "v"(v) : "memory");
}
__device__ __forceinline__ void st_flag(int* p, int v) {
  asm volatile("global_store_dword %0, %1, off sc0 sc1" :: "v"(p), "v"(v) : "memory");
}
// 16 coherent dwordx4 loads (2 A-rows x 8 k-chunks); waitcnt INSIDE the asm
// block so outputs are final when it retires (no reorder/spill hazard).
__device__ __forceinline__ void ld_hist16(const short* p0, const short* p1,
                                          bf16x8* afr0, bf16x8* afr1) {
  u32x4 q0,q1,q2,q3,q4,q5,q6,q7,q8,q9,q10,q11,q12,q13,q14,q15;
  asm volatile(
    "global_load_dwordx4 %0, %16, off sc0 sc1\n\t"
    "global_load_dwordx4 %1, %16, off offset:64 sc0 sc1\n\t"
    "global_load_dwordx4 %2, %16, off offset:128 sc0 sc1\n\t"
    "global_load_dwordx4 %3, %16, off offset:192 sc0 sc1\n\t"
    "global_load_dwordx4 %4, %16, off offset:256 sc0 sc1\n\t"
    "global_load_dwordx4 %5, %16, off offset:320 sc0 sc1\n\t"
    "global_load_dwordx4 %6, %16, off offset:384 sc0 sc1\n\t"
    "global_load_dwordx4 %7, %16, off offset:448 sc0 sc1\n\t"
    "global_load_dwordx4 %8, %17, off sc0 sc1\n\t"
    "global_load_dwordx4 %9, %17, off offset:64 sc0 sc1\n\t"
    "global_load_dwordx4 %10, %17, off offset:128 sc0 sc1\n\t"
    "global_load_dwordx4 %11, %17, off offset:192 sc0 sc1\n\t"
    "global_load_dwordx4 %12, %17, off offset:256 sc0 sc1\n\t"
    "global_load_dwordx4 %13, %17, off offset:320 sc0 sc1\n\t"
    "global_load_dwordx4 %14, %17, off offset:384 sc0 sc1\n\t"
    "global_load_dwordx4 %15, %17, off offset:448 sc0 sc1\n\t"
    "s_waitcnt vmcnt(0)"
    : "=&v"(q0),"=&v"(q1),"=&v"(q2),"=&v"(q3),"=&v"(q4),"=&v"(q5),"=&v"(q6),"=&v"(q7),
      "=&v"(q8),"=&v"(q9),"=&v"(q10),"=&v"(q11),"=&v"(q12),"=&v"(q13),"=&v"(q14),"=&v"(q15)
    : "v"(p0), "v"(p1)
    : "memory");
  union U { u32x4 u; bf16x8 b; } cv;
  cv.u=q0;  afr0[0]=cv.b; cv.u=q1;  afr0[1]=cv.b; cv.u=q2;  afr0[2]=cv.b; cv.u=q3;  afr0[3]=cv.b;
  cv.u=q4;  afr0[4]=cv.b; cv.u=q5;  afr0[5]=cv.b; cv.u=q6;  afr0[6]=cv.b; cv.u=q7;  afr0[7]=cv.b;
  cv.u=q8;  afr1[0]=cv.b; cv.u=q9;  afr1[1]=cv.b; cv.u=q10; afr1[2]=cv.b; cv.u=q11; afr1[3]=cv.b;
  cv.u=q12; afr1[4]=cv.b; cv.u=q13; afr1[5]=cv.b; cv.u=q14; afr1[6]=cv.b; cv.u=q15; afr1[7]=cv.b;
}

// ---------------- embedding gather + mask ----------------
__global__ void k_embed(const int* __restrict__ x, const float* __restrict__ tab,
                        unsigned short* __restrict__ emb, int* __restrict__ mask) {
  int t = blockIdx.x, b = blockIdx.y;
  int tok = x[b * S_LEN + t];
  if (threadIdx.x == 0) mask[t * NB + b] = (tok != 0);
  const float4* src = (const float4*)(tab + (size_t)tok * UDIM);
  ushort4* dst = (ushort4*)(emb + ((size_t)t * NB + b) * UDIM);
  int i = threadIdx.x;                   // 128 threads * 4 floats = 512
  float4 v = src[i];
  ushort4 o;
  o.x = f2bf(v.x); o.y = f2bf(v.y); o.z = f2bf(v.z); o.w = f2bf(v.w);
  dst[i] = o;
}

// ---------------- weight transpose/convert ----------------
__global__ void k_wprep(WPtrs wp, unsigned short* __restrict__ wsW) {
  int bid = blockIdx.x;
  int kt = bid & 31; bid >>= 5;
  int g  = bid % 3;  bid /= 3;
  int wg = bid & 31; bid >>= 5;
  int slab = bid;                        // 0..7 : (chain, mat)
  const float* src = wp.p[slab];
  int tid = threadIdx.x;
  int r = tid >> 4, cc = tid & 15;
  __shared__ float ldsT[16][17];
  ldsT[cc][r] = src[(size_t)(kt * 16 + r) * 1536 + g * 512 + wg * 16 + cc];
  __syncthreads();
  size_t off = ((size_t)slab * WGS + wg) * (48 * 512) + (size_t)(g * 16 + r) * 512 + kt * 16 + cc;
  wsW[off] = f2bf(ldsT[r][cc]);
}

// ---------------- persistent recurrent kernel ----------------
// chains: 0=fw_l0 1=fw_l1 2=bw_l0 3=bw_l1. 32 WGs/chain, each owns 16 h-cols.
// waves: 0:(x@k,Klo) 1:(h@rk,Klo) 2:(x@k,Khi) 3:(h@rk,Khi)
// R7 = R2 with a lean publish path: drain covers ONLY h-stores; out-writes
// are issued after the flag; flag/shadow polls spin hot (no s_sleep).
__global__ __launch_bounds__(256, 1) void k_rnn(
    const unsigned short* __restrict__ wsW, const unsigned short* __restrict__ emb,
    unsigned short* __restrict__ hist, const int* __restrict__ mask,
    int* __restrict__ flags, const float* __restrict__ state,
    BPtrs bp, float* __restrict__ out) {
  __shared__ short sW[2 * 48 * 512];      // 98304 B, XOR-swizzled rows
  __shared__ float sAcc[2][2][32][48];    // [khalf][mat]
  __shared__ float sBias[2][48];
  __shared__ unsigned char sMask[S_LEN][NB];

  int tid = threadIdx.x;
  int bid = blockIdx.x;
  int xcd = bid & 7;                      // perf heuristic only
  int c = xcd >> 1;                       // chain
  int w = ((bid >> 3) << 1) | (xcd & 1);  // wg-in-chain 0..31
  int layer = c & 1;
  bool back = (c >= 2);
  int lane = tid & 63;
  int wave = tid >> 6;
  int mat = wave & 1;                     // 0: x@k, 1: h@rk
  int kh = wave >> 1;                     // K-half

  // combine-phase ownership: thread -> (b, j0, j0+1); h and prev in registers
  int cb = tid >> 3;
  int cj = (tid & 7) << 1;
  float hreg0, hreg1, preg0 = 0.f, preg1 = 0.f;

  // ---- init: weights -> LDS (swizzled), biases, mask, state ----
  {
    const size_t slabSz = 48 * 512;
    for (int ch = tid; ch < 2 * 48 * 64; ch += 256) {
      int m = ch / (48 * 64);
      int rem = ch % (48 * 64);
      int nl = rem >> 6;
      int k16 = rem & 63;
      const unsigned short* sp =
          wsW + ((size_t)((c * 2 + m) * WGS) + w) * slabSz + (size_t)nl * 512 + k16 * 8;
      bf16x8 val = *(const bf16x8*)sp;
      int byte = m * 49152 + nl * 1024 + ((k16 * 16) ^ ((nl & 7) << 4));
      *(bf16x8*)((char*)sW + byte) = val;
    }
    const float* bptr = bp.p[c];
    for (int i = tid; i < 96; i += 256) {
      int m = i / 48, nl = i % 48;
      int col = (nl / 16) * 512 + w * 16 + (nl & 15);
      sBias[m][nl] = bptr[m * 1536 + col];
    }
    for (int i = tid; i < S_LEN * NB; i += 256)
      sMask[i >> 5][i & 31] = (unsigned char)(mask[i] != 0);
    // state -> h registers + publish hist slot 0 (coherent)
    int col = w * 16 + cj;
    hreg0 = state[((size_t)c * NB + cb) * UDIM + col];
    hreg1 = state[((size_t)c * NB + cb) * UDIM + col + 1];
    unsigned pk = (unsigned)f2bf(hreg0) | ((unsigned)f2bf(hreg1) << 16);
    st_u32c((unsigned*)(hist + (((size_t)c * 257) * NB + cb) * UDIM + col), pk);
  }
  asm volatile("s_waitcnt vmcnt(0)" ::: "memory");
  __syncthreads();
  if (tid == 0) st_flag(&flags[(c * 257) * 32 + w], 1);

  for (int t = 0; t < S_LEN; ++t) {
    int treal = back ? (S_LEN - 1 - t) : t;
    const unsigned short* arow;
    const int* fl = nullptr;
    int ownIdx = -1;
    if (mat == 0) {
      if (layer == 0) {
        arow = emb + (size_t)treal * NB * UDIM;
      } else {
        arow = hist + ((size_t)(c - 1) * 257 + (t + 1)) * NB * UDIM;
        fl = flags + ((c - 1) * 257 + (t + 1)) * 32;
      }
    } else {
      arow = hist + ((size_t)c * 257 + t) * NB * UDIM;
      fl = flags + (c * 257 + t) * 32;
      ownIdx = w;   // our own slice is self-visible (stored + vmcnt'd by us)
    }

    int r15 = lane & 15, quad = lane >> 4;
    const short* a16 = (const short*)arow;
    int abase = r15 * UDIM + kh * 256 + quad * 8;

    bf16x8 afr0[8], afr1[8];
    if (fl) {  // wave-uniform; hot spin (no sleep) on 32 single-writer flags
      const int* fp = fl + (lane & 31);
      bool sub = ((lane & 31) == ownIdx);
      int v = sub ? 1 : ld_flag(fp);
      while (!__all(v != 0)) {
        v = sub ? 1 : ld_flag(fp);
      }
      ld_hist16((const short*)(a16 + abase), (const short*)(a16 + abase + 16 * UDIM),
                afr0, afr1);
    } else {
#pragma unroll
      for (int kc = 0; kc < 8; ++kc) {
        afr0[kc] = *(const bf16x8*)(a16 + abase + kc * 32);
        afr1[kc] = *(const bf16x8*)(a16 + abase + 16 * UDIM + kc * 32);
      }
    }

    // GEMM: (32 x 48) += A(32 x 256-half) * W(256-half x 48)
    f32x4 acc[2][3];
#pragma unroll
    for (int a = 0; a < 2; a++)
#pragma unroll
      for (int g = 0; g < 3; g++) acc[a][g] = (f32x4){0.f, 0.f, 0.f, 0.f};
    int matbase = mat * 49152;
#pragma unroll
    for (int kc = 0; kc < 8; ++kc) {
#pragma unroll
      for (int g = 0; g < 3; ++g) {
        int nl = g * 16 + r15;
        int koff = kh * 512 + kc * 64 + quad * 16;
        int byte = matbase + nl * 1024 + (koff ^ ((nl & 7) << 4));
        bf16x8 bw = *(const bf16x8*)((const char*)sW + byte);
        acc[0][g] = __builtin_amdgcn_mfma_f32_16x16x32_bf16(afr0[kc], bw, acc[0][g], 0, 0, 0);
        acc[1][g] = __builtin_amdgcn_mfma_f32_16x16x32_bf16(afr1[kc], bw, acc[1][g], 0, 0, 0);
      }
    }
#pragma unroll
    for (int mt = 0; mt < 2; ++mt)
#pragma unroll
      for (int g = 0; g < 3; ++g)
#pragma unroll
        for (int rr = 0; rr < 4; ++rr)
          sAcc[kh][mat][mt * 16 + quad * 4 + rr][g * 16 + r15] = acc[mt][g][rr];
    __syncthreads();

    // combine + GRU nonlinearity: this thread owns (cb, cj) and (cb, cj+1)
    float hn0, hn1, o0, o1;
    bool mk;
    {
      int b = cb, j0 = cj;
      mk = sMask[treal][b] != 0;
#pragma unroll
      for (int u = 0; u < 2; ++u) {
        int j = j0 + u;
        float az = sAcc[0][0][b][j]      + sAcc[1][0][b][j]      + sBias[0][j];
        float ar = sAcc[0][0][b][16 + j] + sAcc[1][0][b][16 + j] + sBias[0][16 + j];
        float ah = sAcc[0][0][b][32 + j] + sAcc[1][0][b][32 + j] + sBias[0][32 + j];
        float iz = sAcc[0][1][b][j]      + sAcc[1][1][b][j]      + sBias[1][j];
        float ir = sAcc[0][1][b][16 + j] + sAcc[1][1][b][16 + j] + sBias[1][16 + j];
        float ih = sAcc[0][1][b][32 + j] + sAcc[1][1][b][32 + j] + sBias[1][32 + j];
        float z = 1.f / (1.f + __expf(-(az + iz)));
        float r = 1.f / (1.f + __expf(-(ar + ir)));
        float pre = ah + r * ih;
        pre = fminf(fmaxf(pre, -30.f), 30.f);
        float e2 = __expf(2.f * pre);
        float hh = (e2 - 1.f) / (e2 + 1.f);
        float hold = (u == 0) ? hreg0 : hreg1;
        float hv = z * hold + (1.f - z) * hh;
        hv = mk ? hv : hold;
        if (u == 0) hn0 = hv; else hn1 = hv;
      }
      hreg0 = hn0; hreg1 = hn1;
      // ---- publish path: ONLY the h-store before the drain ----
      unsigned pk = (unsigned)f2bf(hn0) | ((unsigned)f2bf(hn1) << 16);
      st_u32c((unsigned*)(hist + (((size_t)c * 257 + (t + 1)) * NB + cb) * UDIM + w * 16 + j0), pk);
    }
    asm volatile("s_waitcnt vmcnt(0)" ::: "memory");   // drain h-stores only
    __syncthreads();
    if (tid == 0) st_flag(&flags[(c * 257 + (t + 1)) * 32 + w], 1);

    // ---- out-writes AFTER the flag (off the publish critical path) ----
    if (layer == 1) {
      o0 = mk ? hn0 : preg0;
      o1 = mk ? hn1 : preg1;
      preg0 = o0; preg1 = o1;
      *(float2*)(out + ((size_t)cb * S_LEN + treal) * 1024 + (back ? 512 : 0) + w * 16 + cj) =
          make_float2(o0, o1);
    }
    if (t == S_LEN - 1) {
      *(float2*)(out + (size_t)NB * S_LEN * 1024 + ((size_t)c * NB + cb) * UDIM + w * 16 + cj) =
          make_float2(hn0, hn1);
    }
  }
}

extern "C" void kernel_launch(void* const* d_in, const int* in_sizes, int n_in,
                              void* d_out, int out_size, void* d_ws, size_t ws_size,
                              hipStream_t stream) {
  const int* x = (const int*)d_in[0];
  const float* state = (const float*)d_in[1];
  const float* tab = (const float*)d_in[2];
  WPtrs wp;
  wp.p[0] = (const float*)d_in[3];   // fk0
  wp.p[1] = (const float*)d_in[4];   // frk0
  wp.p[2] = (const float*)d_in[6];   // fk1
  wp.p[3] = (const float*)d_in[7];   // frk1
  wp.p[4] = (const float*)d_in[9];   // bk0
  wp.p[5] = (const float*)d_in[10];  // brk0
  wp.p[6] = (const float*)d_in[12];  // bk1
  wp.p[7] = (const float*)d_in[13];  // brk1
  BPtrs bp;
  bp.p[0] = (const float*)d_in[5];   // fb0
  bp.p[1] = (const float*)d_in[8];   // fb1
  bp.p[2] = (const float*)d_in[11];  // bb0
  bp.p[3] = (const float*)d_in[14];  // bb1
  float* out = (float*)d_out;

  char* ws = (char*)d_ws;
  size_t off = 0;
  unsigned short* wsW = (unsigned short*)(ws + off); off += (size_t)8 * 32 * 48 * 512 * 2;
  unsigned short* embp = (unsigned short*)(ws + off); off += (size_t)S_LEN * NB * UDIM * 2;
  unsigned short* hist = (unsigned short*)(ws + off); off += (size_t)4 * 257 * NB * UDIM * 2;
  int* maskp = (int*)(ws + off); off += (size_t)S_LEN * NB * 4;
  int* flags = (int*)(ws + off); off += (size_t)4 * 257 * 32 * 4;

  hipMemsetAsync(flags, 0, (size_t)4 * 257 * 32 * 4, stream);
  k_embed<<<dim3(S_LEN, NB), 128, 0, stream>>>(x, tab, embp, maskp);
  k_wprep<<<8 * 32 * 3 * 32, 256, 0, stream>>>(wp, wsW);
  k_rnn<<<128, 256, 0, stream>>>(wsW, embp, hist, maskp, flags, state, bp, out);
}